// Round 3
// baseline (362.356 us; speedup 1.0000x reference)
//
#include <hip/hip_runtime.h>
#include <hip/hip_cooperative_groups.h>

namespace cg = cooperative_groups;

#define B 8
#define N 1024
#define E 10
#define LDE 20     // padded row stride (floats) for base/emb workspace buffers
#define NB 256     // blocks  (1 per CU; coop launch validates residency)
#define NT 512     // threads per block (8 waves)
#define TILE 32    // rows per block
#define CH 256     // Em rows per staged chunk
#define NCH 4      // chunks per iteration (N / CH)

// One persistent cooperative kernel:
//   phase 0: column-sums of W -> base, emb0         (exact relu(w*c) collapse)
//   phase 1..4: emb_{t+1} = relu(base + Wp * (A @ emb_t)), A held in registers
//   phase 5: q_vals
__global__ __launch_bounds__(NT, 2) void k_all(
    const float* __restrict__ W, const float* __restrict__ features,
    const float* __restrict__ A, const float* __restrict__ w_sel,
    const float* __restrict__ w_pri, const float* __restrict__ w_nbw,
    const float* __restrict__ w_ew, const float* __restrict__ w_reduc,
    const float* __restrict__ w_all, const float* __restrict__ w_act,
    float* __restrict__ basePad, float* __restrict__ eA, float* __restrict__ eB,
    float* __restrict__ qsum, float* __restrict__ qv, float* __restrict__ emb_out)
{
    __shared__ float Em[2][CH][LDE];     // 40 KB double-buffered Em chunk
    __shared__ float vred[8][4][80];     // 10 KB cross-wave reduction
    __shared__ float red[2][16][32];     // 4 KB base-phase partials
    __shared__ float scol[2][32];
    __shared__ float WpS[E * E];
    __shared__ float wred[8];

    cg::grid_group grid = cg::this_grid();
    int tid = threadIdx.x, bx = blockIdx.x;
    int b = bx >> 5;          // 8 batches x 32 tiles
    int tile = bx & 31;
    int i0 = tile * TILE;
    int m = tid & 3;          // row residue: rows m+4k, k=0..7
    int s = tid >> 2;         // j-stream 0..127

    if (tid < E * E) WpS[tid] = w_pri[tid];

    // ---- A tile into registers: row (m+4k), col (s + 128*cj). Loaded once,
    // reused by all 4 iterations (no per-iteration A traffic at all).
    float Ar[8][8];
    const float* Ab = A + (size_t)(b * N + i0) * N;
#pragma unroll
    for (int k = 0; k < 8; ++k)
#pragma unroll
        for (int cj = 0; cj < 8; ++cj)
            Ar[k][cj] = Ab[(size_t)(m + 4 * k) * N + (s + 128 * cj)];

    // ---- phase 0: base. Block (b, tile) handles cols c0..c0+31 of batch b.
    {
        int c0 = tile * 32;
        int col = tid & 31, rg = tid >> 5;   // 16 row-groups x 64 rows
        const float* wp = W + ((size_t)b * N + rg * 64) * N + c0 + col;
        float sp = 0.f, sn = 0.f;
#pragma unroll 8
        for (int i = 0; i < 64; ++i) {
            float w = wp[(size_t)i * N];
            sp += fmaxf(w, 0.f);
            sn += fmaxf(-w, 0.f);
        }
        red[0][rg][col] = sp;
        red[1][rg][col] = sn;
        __syncthreads();
        if (tid < 64) {
            int which = tid >> 5, cc = tid & 31;
            float t = 0.f;
#pragma unroll
            for (int g = 0; g < 16; ++g) t += red[which][g][cc];
            scol[which][cc] = t;
        }
        __syncthreads();
        for (int qq = tid; qq < 32 * E; qq += NT) {
            int cc = qq / E, f = qq % E;
            float spc = scol[0][cc], snc = scol[1][cc];
            float feat = features[(b << 10) + c0 + cc];
            float acc = feat * w_sel[f];
#pragma unroll
            for (int e = 0; e < E; ++e) {
                float c = w_ew[e];
                float se = (c > 0.f) ? c * spc : (-c) * snc;
                acc += w_nbw[f * E + e] * se;
            }
            size_t gi = (size_t)((b << 10) + c0 + cc);
            basePad[gi * LDE + f] = acc;
            eA[gi * LDE + f] = fmaxf(acc, 0.f);   // emb0 = relu(base)
        }
        if (bx == 0 && tid < B) qsum[tid] = 0.f;
    }
    grid.sync();

    // ---- phases 1..4: iterations
    float rsave = 0.f;
#pragma unroll 1
    for (int it = 0; it < 4; ++it) {
        const float* ein = (it & 1) ? eB : eA;
        float* eout      = (it & 1) ? eA : eB;
        const float* Ebase = ein + (size_t)b * N * LDE;

        float acc[8][E];
#pragma unroll
        for (int k = 0; k < 8; ++k)
#pragma unroll
            for (int e = 0; e < E; ++e) acc[k][e] = 0.f;

        // prefetch + store chunk 0 (1280 float4 per chunk)
        float4 pa0, pa1, pa2;
        {
            const float4* src = (const float4*)(Ebase);
            pa0 = src[tid];
            pa1 = src[tid + NT];
            if (tid < 256) pa2 = src[tid + 2 * NT];
            float4* dst = (float4*)(&Em[0][0][0]);
            dst[tid] = pa0;
            dst[tid + NT] = pa1;
            if (tid < 256) dst[tid + 2 * NT] = pa2;
        }

        for (int c = 0; c < NCH; ++c) {
            __syncthreads();   // buf c&1 ready; reads of buf (c+1)&1 finished
            if (c < NCH - 1) { // issue global prefetch for next chunk
                const float4* src = (const float4*)(Ebase + (size_t)(c + 1) * CH * LDE);
                pa0 = src[tid];
                pa1 = src[tid + NT];
                if (tid < 256) pa2 = src[tid + 2 * NT];
            }
#pragma unroll
            for (int jj = 0; jj < 2; ++jj) {
                const float* er = &Em[c & 1][jj * 128 + s][0];
                float4 e0 = *(const float4*)(er);
                float4 e1 = *(const float4*)(er + 4);
                float2 e2 = *(const float2*)(er + 8);
                int cj = 2 * c + jj;
#pragma unroll
                for (int k = 0; k < 8; ++k) {
                    float a = Ar[k][cj];
                    acc[k][0] += a * e0.x; acc[k][1] += a * e0.y;
                    acc[k][2] += a * e0.z; acc[k][3] += a * e0.w;
                    acc[k][4] += a * e1.x; acc[k][5] += a * e1.y;
                    acc[k][6] += a * e1.z; acc[k][7] += a * e1.w;
                    acc[k][8] += a * e2.x; acc[k][9] += a * e2.y;
                }
            }
            if (c < NCH - 1) { // write next chunk into the other buffer
                float4* dst = (float4*)(&Em[(c + 1) & 1][0][0]);
                dst[tid] = pa0;
                dst[tid + NT] = pa1;
                if (tid < 256) dst[tid + 2 * NT] = pa2;
            }
        }

        // reduce the 16 s-streams within each wave (lanes differing in bits 2..5)
#pragma unroll
        for (int mask = 4; mask <= 32; mask <<= 1)
#pragma unroll
            for (int k = 0; k < 8; ++k)
#pragma unroll
                for (int e = 0; e < E; ++e)
                    acc[k][e] += __shfl_xor(acc[k][e], mask, 64);

        int w = tid >> 6, l = tid & 63;
        if (l < 4) {   // lane l holds m=l partials (s-block of this wave)
#pragma unroll
            for (int k = 0; k < 8; ++k)
#pragma unroll
                for (int e = 0; e < E; ++e)
                    vred[w][l][k * E + e] = acc[k][e];
        }
        __syncthreads();

        float contrib = 0.f;
        if (tid < TILE * E) {   // 320 threads: (row, f)
            int row = tid / E, f = tid % E;
            int mm = row & 3, kk = row >> 2;
            float d = 0.f;
#pragma unroll
            for (int e = 0; e < E; ++e) {
                float v = 0.f;
#pragma unroll
                for (int w2 = 0; w2 < 8; ++w2) v += vred[w2][mm][kk * E + e];
                d += v * WpS[f * E + e];
            }
            size_t gi = (size_t)(b * N + i0 + row);
            float r = fmaxf(basePad[gi * LDE + f] + d, 0.f);
            if (it < 3) {
                eout[gi * LDE + f] = r;
            } else {
                emb_out[gi * E + f] = r;   // compact final layout in d_out
                rsave = r;
                float ga = 0.f;
#pragma unroll
                for (int k = 0; k < E; ++k) ga += w_reduc[k] * w_all[k * E + f];
                contrib = r * ga;
            }
        }
        if (it == 3) {
#pragma unroll
            for (int off = 32; off >= 1; off >>= 1)
                contrib += __shfl_down(contrib, off, 64);
            if (l == 0) wred[w] = contrib;
            __syncthreads();
            if (tid == 0) {
                float t = 0.f;
#pragma unroll
                for (int w2 = 0; w2 < 8; ++w2) t += wred[w2];
                atomicAdd(&qsum[b], t);
            }
        }
        grid.sync();
    }

    // ---- phase 5: q_vals (qsum complete after final grid.sync)
    float* qred = &vred[0][0][0];   // reuse as [32][10]
    if (tid < TILE * E) {
        int row = tid / E, f = tid % E;
        float ga = 0.f;
#pragma unroll
        for (int k = 0; k < E; ++k) ga += w_reduc[E + k] * w_act[k * E + f];
        qred[row * E + f] = rsave * ga;
    }
    __syncthreads();
    if (tid < TILE) {
        float d = 0.f;
#pragma unroll
        for (int f = 0; f < E; ++f) d += qred[tid * E + f];
        qv[(b << 10) + i0 + tid] = qsum[b] + d;
    }
}

extern "C" void kernel_launch(void* const* d_in, const int* in_sizes, int n_in,
                              void* d_out, int out_size, void* d_ws, size_t ws_size,
                              hipStream_t stream) {
    const float* W         = (const float*)d_in[0 + 1];  // weights
    const float* features  = (const float*)d_in[0];
    const float* adjacency = (const float*)d_in[2];
    const float* w_sel     = (const float*)d_in[3];
    const float* w_pri     = (const float*)d_in[4];
    const float* w_nbw     = (const float*)d_in[5];
    const float* w_ew      = (const float*)d_in[6];
    const float* w_reduc   = (const float*)d_in[7];
    const float* w_all     = (const float*)d_in[8];
    const float* w_act     = (const float*)d_in[9];

    float* out     = (float*)d_out;
    float* qv      = out;              // B*N
    float* emb_out = out + B * N;      // B*N*E

    float* ws      = (float*)d_ws;
    float* basePad = ws;                               // B*N*LDE
    float* eA      = basePad + (size_t)B * N * LDE;    // B*N*LDE
    float* eB      = eA + (size_t)B * N * LDE;         // B*N*LDE
    float* qsum    = eB + (size_t)B * N * LDE;         // 8

    void* args[] = { (void*)&W, (void*)&features, (void*)&adjacency,
                     (void*)&w_sel, (void*)&w_pri, (void*)&w_nbw, (void*)&w_ew,
                     (void*)&w_reduc, (void*)&w_all, (void*)&w_act,
                     (void*)&basePad, (void*)&eA, (void*)&eB,
                     (void*)&qsum, (void*)&qv, (void*)&emb_out };
    hipLaunchCooperativeKernel((void*)k_all, dim3(NB), dim3(NT), args, 0, stream);
}

// Round 4
// 304.415 us; speedup vs baseline: 1.1903x; 1.1903x over previous
//
#include <hip/hip_runtime.h>
#include <hip/hip_cooperative_groups.h>

namespace cg = cooperative_groups;

#define B 8
#define N 1024
#define E 10
#define NB 256        // blocks: 8 batches x 32 tiles; 1 block/CU
#define NT 512        // threads: 8 waves
#define TILE 32       // output rows per block
#define GP 44         // floats per 4-row emb group (40 data + 4 pad; 8 bank-starts)
#define NGRP 256      // groups per batch (1024 rows / 4)
#define EMB_FLOATS (NGRP * GP)      // 11264 floats per batch
#define EMB_F4 (EMB_FLOATS / 4)     // 2816 float4 per batch

// Single cooperative kernel.
//  phase 0: colsums of W -> base (LDS) + emb0 (global, group-padded)
//           [exact: sum_i relu(w*c) = c>0 ? c*sum(max(w,0)) : -c*sum(max(-w,0))]
//  it 0..3: emb' = relu(base + Wp @ (A @ emb)); A lives in registers the whole time
//  phase 5: q_vals
__global__ __launch_bounds__(NT, 1) void k_all(
    const float* __restrict__ W, const float* __restrict__ features,
    const float* __restrict__ A, const float* __restrict__ w_sel,
    const float* __restrict__ w_pri, const float* __restrict__ w_nbw,
    const float* __restrict__ w_ew, const float* __restrict__ w_reduc,
    const float* __restrict__ w_all, const float* __restrict__ w_act,
    float* __restrict__ eA, float* __restrict__ eB,
    float* __restrict__ qsum, float* __restrict__ qv, float* __restrict__ emb_out)
{
    __shared__ float4 EmS[EMB_F4];        // 45056 B: whole batch emb, group-padded
    __shared__ float vred[8][8][40];      // 10240 B
    __shared__ float red[2][16][32];      // 4096 B (phase 0 only)
    __shared__ float scol[2][32];
    __shared__ float WpS[E * E];
    __shared__ float baseS[TILE * E];     // this block's base rows (stay in LDS)
    __shared__ float vS[TILE * E];
    __shared__ float gaS[E], gactS[E];
    __shared__ float wred[8];

    cg::grid_group grid = cg::this_grid();
    int tid = threadIdx.x, bx = blockIdx.x;
    int b = bx >> 5, tile = bx & 31;
    int i0 = tile * TILE;
    int m = tid >> 6;     // wave 0..7: rows i0 + m + 8k
    int s = tid & 63;     // lane: cols 256c + 4s + q

    // ---- A tile into registers (perfect float4 coalescing), reused 4 iters
    float Arf[4][4][4];
    {
        const float* Ab = A + ((size_t)(b * N) + i0 + m) * N + 4 * s;
#pragma unroll
        for (int k = 0; k < 4; ++k)
#pragma unroll
            for (int c = 0; c < 4; ++c) {
                float4 t = *(const float4*)(Ab + (size_t)(8 * k) * N + 256 * c);
                Arf[k][c][0] = t.x; Arf[k][c][1] = t.y;
                Arf[k][c][2] = t.z; Arf[k][c][3] = t.w;
            }
    }

    if (tid < E * E) WpS[tid] = w_pri[tid];
    if (tid < E) {
        float sa = 0.f, sc = 0.f;
#pragma unroll
        for (int k = 0; k < E; ++k) {
            sa += w_reduc[k] * w_all[k * E + tid];
            sc += w_reduc[E + k] * w_act[k * E + tid];
        }
        gaS[tid] = sa;
        gactS[tid] = sc;
    }
    if (bx == 0 && tid < B) qsum[tid] = 0.f;

    // ---- phase 0: base for THIS block's 32 node indices (cols c0..c0+31 of W)
    {
        int c0 = i0;                       // node indices match our row tile
        int col = tid & 31, rg = tid >> 5; // 16 row-groups x 64 rows
        const float* wp = W + ((size_t)b * N + rg * 64) * N + c0 + col;
        float sp = 0.f, sn = 0.f;
#pragma unroll 8
        for (int i = 0; i < 64; ++i) {
            float w = wp[(size_t)i * N];
            sp += fmaxf(w, 0.f);
            sn += fmaxf(-w, 0.f);
        }
        red[0][rg][col] = sp;
        red[1][rg][col] = sn;
        __syncthreads();
        if (tid < 64) {
            int which = tid >> 5, cc = tid & 31;
            float t = 0.f;
#pragma unroll
            for (int g = 0; g < 16; ++g) t += red[which][g][cc];
            scol[which][cc] = t;
        }
        __syncthreads();
        if (tid < TILE * E) {
            int cc = tid / E, f = tid % E;
            float spc = scol[0][cc], snc = scol[1][cc];
            float acc = features[(b << 10) + c0 + cc] * w_sel[f];
#pragma unroll
            for (int e = 0; e < E; ++e) {
                float c = w_ew[e];
                float se = (c > 0.f) ? c * spc : (-c) * snc;
                acc += w_nbw[f * E + e] * se;
            }
            baseS[tid] = acc;
            int row = c0 + cc;
            eA[(size_t)b * EMB_FLOATS + (row >> 2) * GP + (row & 3) * E + f] =
                fmaxf(acc, 0.f);           // emb0 = relu(base)
        }
    }
    grid.sync();

    // ---- iterations
    float rsave = 0.f;
#pragma unroll 1
    for (int it = 0; it < 4; ++it) {
        const float* ein = (it & 1) ? eB : eA;
        float* eout      = (it & 1) ? eA : eB;

        // stage the whole batch's emb (44 KB), straight float4 copy
        const float4* src = (const float4*)(ein + (size_t)b * EMB_FLOATS);
        for (int u = tid; u < EMB_F4; u += NT) EmS[u] = src[u];
        __syncthreads();

        float acc[4][E];
#pragma unroll
        for (int k = 0; k < 4; ++k)
#pragma unroll
            for (int e = 0; e < E; ++e) acc[k][e] = 0.f;

#pragma unroll
        for (int c = 0; c < 4; ++c) {
            float g40[40];
            float4* g4 = (float4*)g40;
            const float4* gp = &EmS[(64 * c + s) * (GP / 4)];
#pragma unroll
            for (int t = 0; t < 10; ++t) g4[t] = gp[t];
#pragma unroll
            for (int q = 0; q < 4; ++q)
#pragma unroll
                for (int k = 0; k < 4; ++k) {
                    float a = Arf[k][c][q];
#pragma unroll
                    for (int e = 0; e < E; ++e)
                        acc[k][e] += a * g40[q * E + e];
                }
        }

        // reduce lanes within aligned 8-groups (masks 1,2,4)
#pragma unroll
        for (int mask = 1; mask <= 4; mask <<= 1)
#pragma unroll
            for (int k = 0; k < 4; ++k)
#pragma unroll
                for (int e = 0; e < E; ++e)
                    acc[k][e] += __shfl_xor(acc[k][e], mask, 64);
        if ((s & 7) == 0)
#pragma unroll
            for (int k = 0; k < 4; ++k)
#pragma unroll
                for (int e = 0; e < E; ++e)
                    vred[m][s >> 3][k * E + e] = acc[k][e];
        __syncthreads();

        if (tid < TILE * E) {              // (row, e): finish v sums
            int row = tid / E, e = tid % E;
            int mm = row & 7, kk = row >> 3;
            float v = 0.f;
#pragma unroll
            for (int g = 0; g < 8; ++g) v += vred[mm][g][kk * E + e];
            vS[tid] = v;
        }
        __syncthreads();

        float contrib = 0.f;
        if (tid < TILE * E) {              // (row, f): Wp, base, relu, store
            int row = tid / E, f = tid % E;
            float d = 0.f;
#pragma unroll
            for (int e = 0; e < E; ++e) d += vS[row * E + e] * WpS[f * E + e];
            float r = fmaxf(baseS[tid] + d, 0.f);
            if (it < 3) {
                int grow = i0 + row;
                eout[(size_t)b * EMB_FLOATS + (grow >> 2) * GP + (grow & 3) * E + f] = r;
            } else {
                emb_out[((size_t)(b << 10) + i0 + row) * E + f] = r;
                rsave = r;
                contrib = r * gaS[f];
            }
        }
        if (it == 3) {
#pragma unroll
            for (int off = 32; off >= 1; off >>= 1)
                contrib += __shfl_down(contrib, off, 64);
            if (s == 0) wred[m] = contrib;
            __syncthreads();
            if (tid == 0) {
                float t = 0.f;
#pragma unroll
                for (int w = 0; w < 8; ++w) t += wred[w];
                atomicAdd(&qsum[b], t);
            }
        }
        grid.sync();
    }

    // ---- phase 5: q_vals
    if (tid < TILE * E) {
        int f = tid % E;
        vS[tid] = rsave * gactS[f];
    }
    __syncthreads();
    if (tid < TILE) {
        float d = 0.f;
#pragma unroll
        for (int f = 0; f < E; ++f) d += vS[tid * E + f];
        qv[(b << 10) + i0 + tid] = qsum[b] + d;
    }
}

extern "C" void kernel_launch(void* const* d_in, const int* in_sizes, int n_in,
                              void* d_out, int out_size, void* d_ws, size_t ws_size,
                              hipStream_t stream) {
    const float* features  = (const float*)d_in[0];
    const float* W         = (const float*)d_in[1];
    const float* adjacency = (const float*)d_in[2];
    const float* w_sel     = (const float*)d_in[3];
    const float* w_pri     = (const float*)d_in[4];
    const float* w_nbw     = (const float*)d_in[5];
    const float* w_ew      = (const float*)d_in[6];
    const float* w_reduc   = (const float*)d_in[7];
    const float* w_all     = (const float*)d_in[8];
    const float* w_act     = (const float*)d_in[9];

    float* out     = (float*)d_out;
    float* qv      = out;              // B*N
    float* emb_out = out + B * N;      // B*N*E

    float* ws   = (float*)d_ws;
    float* eA   = ws;                             // B*EMB_FLOATS (group-padded)
    float* eB   = eA + (size_t)B * EMB_FLOATS;    // B*EMB_FLOATS
    float* qsum = eB + (size_t)B * EMB_FLOATS;    // 8

    void* args[] = { (void*)&W, (void*)&features, (void*)&adjacency,
                     (void*)&w_sel, (void*)&w_pri, (void*)&w_nbw, (void*)&w_ew,
                     (void*)&w_reduc, (void*)&w_all, (void*)&w_act,
                     (void*)&eA, (void*)&eB, (void*)&qsum,
                     (void*)&qv, (void*)&emb_out };
    hipLaunchCooperativeKernel((void*)k_all, dim3(NB), dim3(NT), args, 0, stream);
}

// Round 5
// 157.520 us; speedup vs baseline: 2.3004x; 1.9326x over previous
//
#include <hip/hip_runtime.h>

#define B 8
#define N 1024
#define E 10
#define GP 44                        // 4 emb rows packed in 44 floats (40 data + 4 pad)
#define EMB_FLOATS (256 * GP)        // 11264 floats per batch
#define EMB_F4 (EMB_FLOATS / 4)      // 2816 float4 per batch

// ---------------------------------------------------------------------------
// K1: base + emb0 via exact relu-collapse:
//   sum_i relu(w[i,j]*c) = c>0 ? c*sum_i max(w,0) : (-c)*sum_i max(-w,0)
//   256 blocks (8 b x 32 col-slices of 32) x 512 thr. One 32 MB HBM pass.
// ---------------------------------------------------------------------------
__global__ __launch_bounds__(512) void k_base(
    const float* __restrict__ W, const float* __restrict__ features,
    const float* __restrict__ w_sel, const float* __restrict__ w_nbw,
    const float* __restrict__ w_ew, float* __restrict__ base,
    float* __restrict__ emb0, float* __restrict__ qsum)
{
    __shared__ float red[2][16][32];
    __shared__ float scol[2][32];
    int bx = blockIdx.x, tid = threadIdx.x;
    int b = bx >> 5, c0 = (bx & 31) * 32;
    int col = tid & 31, rg = tid >> 5;     // 16 row-groups x 64 rows
    const float* wp = W + ((size_t)b * N + rg * 64) * N + c0 + col;
    float sp = 0.f, sn = 0.f;
#pragma unroll 8
    for (int i = 0; i < 64; ++i) {
        float w = wp[(size_t)i * N];
        sp += fmaxf(w, 0.f);
        sn += fmaxf(-w, 0.f);
    }
    red[0][rg][col] = sp;
    red[1][rg][col] = sn;
    __syncthreads();
    if (tid < 64) {
        int which = tid >> 5, cc = tid & 31;
        float t = 0.f;
#pragma unroll
        for (int g = 0; g < 16; ++g) t += red[which][g][cc];
        scol[which][cc] = t;
    }
    __syncthreads();
    if (tid < 32 * E) {
        int cc = tid / E, f = tid % E;
        float spc = scol[0][cc], snc = scol[1][cc];
        float acc = features[(b << 10) + c0 + cc] * w_sel[f];
#pragma unroll
        for (int e = 0; e < E; ++e) {
            float c = w_ew[e];
            float se = (c > 0.f) ? c * spc : (-c) * snc;
            acc += w_nbw[f * E + e] * se;
        }
        int row = c0 + cc;
        base[(size_t)((b << 10) + row) * E + f] = acc;
        emb0[(size_t)b * EMB_FLOATS + (row >> 2) * GP + (row & 3) * E + f] =
            fmaxf(acc, 0.f);
    }
    if (bx == 0 && tid < B) qsum[tid] = 0.f;
}

// ---------------------------------------------------------------------------
// K2: one iteration: v = A @ emb; out = relu(base + v @ Wp^T).
//   512 blocks (8 b x 64 tiles of 16 rows) x 256 thr (4 waves, ~3 blocks/CU).
//   Thread (m=tid>>6, s=tid&63): rows i0+m+4k (k<4), cols 4s+q+256c (q<4,c<4).
//   A -> 64 registers via 16 coalesced float4 loads (L3-hot after iter 0).
//   Whole-batch emb (44 KB, group-padded) staged by decoupled float4 copy.
//   FINAL: also writes compact emb_out, q-dact partials, and qsum atomic.
// ---------------------------------------------------------------------------
template <int FINAL>
__global__ __launch_bounds__(256) void k_iter(
    const float* __restrict__ A, const float* __restrict__ ein,
    const float* __restrict__ base, const float* __restrict__ Wp,
    const float* __restrict__ w_reduc, const float* __restrict__ w_all,
    const float* __restrict__ w_act, float* __restrict__ eout,
    float* __restrict__ emb_out, float* __restrict__ qv,
    float* __restrict__ qsum)
{
    __shared__ float4 EmS[EMB_F4];        // 45056 B
    __shared__ float vred[4][8][4 * E];   // 5120 B
    __shared__ float WpS[E * E];
    __shared__ float gaS[E], gactS[E];
    __shared__ float vS[16 * E], qS[16 * E], qrow[16];

    int bx = blockIdx.x, tid = threadIdx.x;
    int b = bx >> 6, tile = bx & 63;
    int i0 = tile * 16;
    int m = tid >> 6;     // wave: rows i0 + m + 4k
    int s = tid & 63;     // lane: cols 4s + q + 256c

    // A tile -> registers (16 independent coalesced float4 loads)
    float Arf[4][4][4];
    {
        const float* Ab = A + ((size_t)(b * N) + i0 + m) * N + 4 * s;
#pragma unroll
        for (int k = 0; k < 4; ++k)
#pragma unroll
            for (int c = 0; c < 4; ++c) {
                float4 t = *(const float4*)(Ab + (size_t)(4 * k) * N + 256 * c);
                Arf[k][c][0] = t.x; Arf[k][c][1] = t.y;
                Arf[k][c][2] = t.z; Arf[k][c][3] = t.w;
            }
    }

    if (tid < E * E) WpS[tid] = Wp[tid];
    if (FINAL && tid < E) {
        float sa = 0.f, sc = 0.f;
#pragma unroll
        for (int k = 0; k < E; ++k) {
            sa += w_reduc[k] * w_all[k * E + tid];
            sc += w_reduc[E + k] * w_act[k * E + tid];
        }
        gaS[tid] = sa;
        gactS[tid] = sc;
    }

    // stage whole-batch emb: 11 decoupled float4 loads, then 11 ds_writes
    {
        const float4* src = (const float4*)ein + (size_t)b * EMB_F4;
        float4 tmp[11];
#pragma unroll
        for (int t = 0; t < 11; ++t) tmp[t] = src[tid + 256 * t];
#pragma unroll
        for (int t = 0; t < 11; ++t) EmS[tid + 256 * t] = tmp[t];
    }
    __syncthreads();

    float acc[4][E];
#pragma unroll
    for (int k = 0; k < 4; ++k)
#pragma unroll
        for (int e = 0; e < E; ++e) acc[k][e] = 0.f;

#pragma unroll
    for (int c = 0; c < 4; ++c) {
        float4 g4[10];
        const float4* gp = EmS + (size_t)(s + 64 * c) * (GP / 4);
#pragma unroll
        for (int t = 0; t < 10; ++t) g4[t] = gp[t];
        const float* g40 = (const float*)g4;
#pragma unroll
        for (int q = 0; q < 4; ++q)
#pragma unroll
            for (int k = 0; k < 4; ++k) {
                float a = Arf[k][c][q];
#pragma unroll
                for (int e = 0; e < E; ++e)
                    acc[k][e] += a * g40[q * E + e];
            }
    }

    // reduce 64 lanes -> 8 partials per wave (masks 1,2,4)
#pragma unroll
    for (int mask = 1; mask <= 4; mask <<= 1)
#pragma unroll
        for (int k = 0; k < 4; ++k)
#pragma unroll
            for (int e = 0; e < E; ++e)
                acc[k][e] += __shfl_xor(acc[k][e], mask, 64);
    if ((s & 7) == 0)
#pragma unroll
        for (int k = 0; k < 4; ++k)
#pragma unroll
            for (int e = 0; e < E; ++e)
                vred[m][s >> 3][k * E + e] = acc[k][e];
    __syncthreads();

    if (tid < 16 * E) {
        int r = tid / E, f = tid % E;
        int mm = r & 3, kk = r >> 2;
        float v[E];
#pragma unroll
        for (int e = 0; e < E; ++e) {
            float t = 0.f;
#pragma unroll
            for (int g = 0; g < 8; ++g) t += vred[mm][g][kk * E + e];
            v[e] = t;
        }
        float d = 0.f;
#pragma unroll
        for (int e = 0; e < E; ++e) d += v[e] * WpS[f * E + e];
        size_t gi = (size_t)((b << 10) + i0 + r);
        float r_out = fmaxf(base[gi * E + f] + d, 0.f);
        if (FINAL) {
            emb_out[gi * E + f] = r_out;
            vS[tid] = r_out * gactS[f];
            qS[tid] = r_out * gaS[f];
        } else {
            int grow = i0 + r;
            eout[(size_t)b * EMB_FLOATS + (grow >> 2) * GP + (grow & 3) * E + f] = r_out;
        }
    }
    if (FINAL) {
        __syncthreads();
        if (tid < 16) {
            float da = 0.f, dg = 0.f;
#pragma unroll
            for (int f = 0; f < E; ++f) {
                da += vS[tid * E + f];
                dg += qS[tid * E + f];
            }
            qv[(b << 10) + i0 + tid] = da;   // dact partial; k_q adds qsum[b]
            qrow[tid] = dg;
        }
        __syncthreads();
        if (tid == 0) {
            float t = 0.f;
#pragma unroll
            for (int r = 0; r < 16; ++r) t += qrow[r];
            atomicAdd(&qsum[b], t);
        }
    }
}

// ---------------------------------------------------------------------------
// K3: qv[g] += qsum[g>>10]
// ---------------------------------------------------------------------------
__global__ __launch_bounds__(256) void k_q(float* __restrict__ qv,
                                           const float* __restrict__ qsum) {
    int g = blockIdx.x * 256 + threadIdx.x;
    qv[g] += qsum[g >> 10];
}

extern "C" void kernel_launch(void* const* d_in, const int* in_sizes, int n_in,
                              void* d_out, int out_size, void* d_ws, size_t ws_size,
                              hipStream_t stream) {
    const float* features  = (const float*)d_in[0];
    const float* W         = (const float*)d_in[1];
    const float* adjacency = (const float*)d_in[2];
    const float* w_sel     = (const float*)d_in[3];
    const float* w_pri     = (const float*)d_in[4];
    const float* w_nbw     = (const float*)d_in[5];
    const float* w_ew      = (const float*)d_in[6];
    const float* w_reduc   = (const float*)d_in[7];
    const float* w_all     = (const float*)d_in[8];
    const float* w_act     = (const float*)d_in[9];

    float* out     = (float*)d_out;
    float* qv      = out;              // B*N
    float* emb_out = out + B * N;      // B*N*E

    float* ws   = (float*)d_ws;
    float* eA   = ws;                              // B*EMB_FLOATS (group-padded)
    float* eB   = eA + (size_t)B * EMB_FLOATS;
    float* base = eB + (size_t)B * EMB_FLOATS;     // B*N*E compact
    float* qsum = base + (size_t)B * N * E;        // 8

    k_base<<<256, 512, 0, stream>>>(W, features, w_sel, w_nbw, w_ew,
                                    base, eA, qsum);
    // ref iter 1 (emb=0) == relu(base) == eA; 4 remaining iterations:
    k_iter<0><<<512, 256, 0, stream>>>(adjacency, eA, base, w_pri, w_reduc,
                                       w_all, w_act, eB, emb_out, qv, qsum);
    k_iter<0><<<512, 256, 0, stream>>>(adjacency, eB, base, w_pri, w_reduc,
                                       w_all, w_act, eA, emb_out, qv, qsum);
    k_iter<0><<<512, 256, 0, stream>>>(adjacency, eA, base, w_pri, w_reduc,
                                       w_all, w_act, eB, emb_out, qv, qsum);
    k_iter<1><<<512, 256, 0, stream>>>(adjacency, eB, base, w_pri, w_reduc,
                                       w_all, w_act, nullptr, emb_out, qv, qsum);
    k_q<<<32, 256, 0, stream>>>(qv, qsum);
}